// Round 6
// baseline (142.720 us; speedup 1.0000x reference)
//
#include <hip/hip_runtime.h>
#include <cmath>

// Caps2dMatwo fused forward: conv3x3 -> pos/app 4x4 transforms -> 3-round routing.
// N=2, T0=4, T1=8, H=W=128, Z=32 (16 pos + 16 app), PD=AD=4.
// R6: 64 lanes per pixel, lane = qp*32 + t*4 + c; lane qp owns u-matrix rows
// i in {qp, qp+2} for BOTH pos and app (preserves shared xv reads).
// Conv weights and transform matrices live in LDS (conflict-free swizzled
// reads) -> per-lane live state ~50 regs, fits 64 VGPRs with no AGPR shuttle.
// Routing reductions fused (no pz array except final iter).

#define TH 4
#define TW 4
#define XR (TH + 2)   // 6 rows incl. halo
#define XC (TW + 2)   // 6 cols incl. halo

__device__ __forceinline__ float qsum4(float v) {
    // sum over the 4 lanes of each quad (lane bits 0-1 = c index)
    int a = __builtin_amdgcn_mov_dpp(__float_as_int(v), 0xB1, 0xF, 0xF, true); // [1,0,3,2]
    v += __int_as_float(a);
    int b = __builtin_amdgcn_mov_dpp(__float_as_int(v), 0x4E, 0xF, 0xF, true); // [2,3,0,1]
    v += __int_as_float(b);
    return v;
}

__global__ __launch_bounds__(256)
void caps_fused(const float* __restrict__ x,    // (2,4,32,128,128)
                const float* __restrict__ Wc,   // (4,3,3,1,8)
                const float* __restrict__ Wp,   // (4,16,8) -> flat [c][128]
                const float* __restrict__ Wa,   // (4,16,8) -> flat [c][128]
                const float* __restrict__ ba,   // (4,8)
                float* __restrict__ out)        // (2,8,32,128,128)
{
    __shared__ float xs[XR][XC][4][36];   // 6*6*4*36*4 = 20736 B
    __shared__ float Mt[32][32];          // 4096 B: per (t*4+c): Mp rows 0-3, Ma rows 4-7 (quad-XOR swizzled)
    __shared__ float Wl[288];             // 1152 B: [c][tap][chp][{wpos,wapp}]

    const int tid = threadIdx.x;
    const int n  = blockIdx.z;
    const int h0 = blockIdx.y * TH;
    const int w0 = blockIdx.x * TW;

    // ---------- stage x halo tile (z-quad XOR swizzle vs banks) ----------
    for (int e = tid; e < 128 * XR * XC; e += 256) {    // 18 iters exactly
        int col = e % XC;
        int tmp = e / XC;
        int row = tmp % XR;
        int cz  = tmp / XR;              // c*32+z
        int gh = h0 - 1 + row;
        int gw = w0 - 1 + col;
        float v = 0.0f;
        if ((unsigned)gh < 128u && (unsigned)gw < 128u)
            v = x[(((size_t)(n * 128 + cz)) << 14) + (gh << 7) + gw];
        int z = cz & 31;
        int s = (row * XC + col) & 7;
        xs[row][col][cz >> 5][(((z >> 2) ^ s) << 2) | (z & 3)] = v;
    }
    // ---------- stage conv weights: Wl[((c*9+tap)*4+chp)*2 + sel] ----------
    for (int e = tid; e < 288; e += 256) {
        int sel = e & 1;
        int chp = (e >> 1) & 3;
        int ctap = e >> 3;               // c*9+tap
        Wl[e] = Wc[ctap * 8 + (sel ? 4 + chp : chp)];
    }
    // ---------- stage transform matrices (32 threads; normalize Mp) ----------
    if (tid < 32) {
        const int ctx = tid;             // t*4+c
        const int cc = ctx & 3, tt = ctx >> 2;
        float Mp[16], Ma[16];
#pragma unroll
        for (int q = 0; q < 16; ++q) {
            Mp[q] = Wp[cc * 128 + tt * 16 + q];   // [j*4+k]
            Ma[q] = Wa[cc * 128 + tt * 16 + q];
        }
#pragma unroll
        for (int k = 0; k < 4; ++k) {
            float s2 = Mp[k] * Mp[k] + Mp[4 + k] * Mp[4 + k]
                     + Mp[8 + k] * Mp[8 + k] + Mp[12 + k] * Mp[12 + k];
            float inv = __builtin_amdgcn_rsqf(fmaxf(s2, 1e-12f));
            Mp[k] *= inv; Mp[4 + k] *= inv; Mp[8 + k] *= inv; Mp[12 + k] *= inv;
        }
        const int swz = ctx & 7;
#pragma unroll
        for (int j = 0; j < 4; ++j)
#pragma unroll
            for (int k = 0; k < 4; ++k) {
                Mt[ctx][((j ^ swz) << 2) + k]       = Mp[j * 4 + k];
                Mt[ctx][(((4 + j) ^ swz) << 2) + k] = Ma[j * 4 + k];
            }
    }

    const int p    = tid >> 6;          // pixel column within tile (0..3)
    const int lane = tid & 63;
    const int c    = lane & 3;          // t0 index
    const int t    = (lane >> 2) & 7;   // output t1 index
    const int qp   = lane >> 5;         // owns u-rows {qp, qp+2}
    const int ct   = lane & 31;         // t*4+c (Mt slot)
    const int sw   = ct & 7;
    const int chp  = t >> 1;            // conv channel (pos); app = 4+chp
    const int zsel = (t & 1) << 2;      // base z-quad

    const float bap = ba[c * 8 + t];
    const float wx  = (float)(w0 + p) * (1.0f / 128.0f);

    __syncthreads();

    for (int g = 0; g < TH; ++g) {
        // ---------- conv 3x3: rows i=qp (u0/a0) and i=qp+2 (u1/a1) ----------
        float u0[4] = {0,0,0,0}, u1[4] = {0,0,0,0};
        float a0[4] = {0,0,0,0}, a1[4] = {0,0,0,0};
        const int gq0 = zsel | qp;
        const int gq1 = zsel | (qp + 2);
#pragma unroll
        for (int dy = 0; dy < 3; ++dy) {
#pragma unroll
            for (int dx = 0; dx < 3; ++dx) {
                const int rr = g + dy, cc2 = p + dx;
                const int s  = (rr * XC + cc2) & 7;
                const float2 wv = *(const float2*)&Wl[((c * 9 + dy * 3 + dx) * 4 + chp) * 2];
                const float* bpx = &xs[rr][cc2][c][0];
                const float4 x0 = *(const float4*)(bpx + ((gq0 ^ s) << 2));
                const float4 x1 = *(const float4*)(bpx + ((gq1 ^ s) << 2));
                u0[0] += x0.x * wv.x; u0[1] += x0.y * wv.x; u0[2] += x0.z * wv.x; u0[3] += x0.w * wv.x;
                a0[0] += x0.x * wv.y; a0[1] += x0.y * wv.y; a0[2] += x0.z * wv.y; a0[3] += x0.w * wv.y;
                u1[0] += x1.x * wv.x; u1[1] += x1.y * wv.x; u1[2] += x1.z * wv.x; u1[3] += x1.w * wv.x;
                a1[0] += x1.x * wv.y; a1[1] += x1.y * wv.y; a1[2] += x1.z * wv.y; a1[3] += x1.w * wv.y;
            }
        }

        // ---------- 4x4 transforms (M streamed from LDS) -> uh[16] ----------
#pragma unroll
        for (int j = 0; j < 4; ++j) { a0[j] += bap; a1[j] += bap; }
        const float hy = (float)(h0 + g) * (1.0f / 128.0f);
        float uh[16];
#pragma unroll
        for (int q = 0; q < 16; ++q) uh[q] = 0.0f;
#pragma unroll
        for (int j = 0; j < 4; ++j) {
            const float4 mp = *(const float4*)&Mt[ct][(j ^ sw) << 2];
            const float4 ma = *(const float4*)&Mt[ct][((4 + j) ^ sw) << 2];
            uh[0]  += u0[j] * mp.x; uh[1]  += u0[j] * mp.y; uh[2]  += u0[j] * mp.z; uh[3]  += u0[j] * mp.w;
            uh[4]  += u1[j] * mp.x; uh[5]  += u1[j] * mp.y; uh[6]  += u1[j] * mp.z; uh[7]  += u1[j] * mp.w;
            uh[8]  += a0[j] * ma.x; uh[9]  += a0[j] * ma.y; uh[10] += a0[j] * ma.z; uh[11] += a0[j] * ma.w;
            uh[12] += a1[j] * ma.x; uh[13] += a1[j] * ma.y; uh[14] += a1[j] * ma.z; uh[15] += a1[j] * ma.w;
        }
        uh[0] += u0[3] * wx;  uh[1] += u0[3] * hy;   // coord offsets (pos row 3)
        uh[4] += u1[3] * wx;  uh[5] += u1[3] * hy;

        // ---------- routing (3 iterations, last one writes out) ----------
        float bacc = 0.0f;
#pragma unroll
        for (int it = 0; it < 3; ++it) {
            const float r = __builtin_amdgcn_rcpf(1.0f + __expf(-bacc));
            float pp[8], pa[8];
            float mxl = 0.0f, sql = 0.0f, dpl = 0.0f, dal = 0.0f;
#pragma unroll
            for (int m = 0; m < 8; ++m) {
                const float pv = qsum4(uh[m] * r);
                pp[m] = pv;                          // DCE'd for it<2
                mxl = fmaxf(mxl, fabsf(pv));
                dpl += uh[m] * pv;
            }
#pragma unroll
            for (int m = 0; m < 8; ++m) {
                const float pv = qsum4(uh[8 + m] * r);
                pa[m] = pv;                          // DCE'd for it<2
                sql += pv * pv;
                dal += uh[8 + m] * pv;
            }
            const float mx = fmaxf(mxl, __shfl_xor(mxl, 32, 64));
            const float sq = sql + __shfl_xor(sql, 32, 64);
            const float invm = __builtin_amdgcn_rcpf(mx);
            const float fac  = sq * __builtin_amdgcn_rcpf(1.0f + sq)
                                  * __builtin_amdgcn_rsqf(sq + 1e-9f);
            if (it < 2) {
                const float dp = dpl + __shfl_xor(dpl, 32, 64);
                const float da = dal + __shfl_xor(dal, 32, 64);
                bacc += (dp * invm) * (da * fac);
            } else if (c == 0) {
                const int row = h0 + g;
                float* ob = out + (((size_t)((n * 8 + t) * 32)) << 14)
                                + (row << 7) + (w0 + p);
#pragma unroll
                for (int ii = 0; ii < 2; ++ii)
#pragma unroll
                    for (int k = 0; k < 4; ++k) {
                        const int z = (qp + 2 * ii) * 4 + k;
                        ob[((size_t)z) << 14]        = pp[ii * 4 + k] * invm;
                        ob[((size_t)(16 + z)) << 14] = pa[ii * 4 + k] * fac;
                    }
            }
        }
    }
}

extern "C" void kernel_launch(void* const* d_in, const int* in_sizes, int n_in,
                              void* d_out, int out_size, void* d_ws, size_t ws_size,
                              hipStream_t stream) {
    const float* x  = (const float*)d_in[0];
    const float* Wc = (const float*)d_in[1];
    const float* Wp = (const float*)d_in[2];
    const float* Wa = (const float*)d_in[3];
    const float* ba = (const float*)d_in[4];
    float* out = (float*)d_out;

    dim3 grid(128 / TW, 128 / TH, 2);   // (32, 32, 2)
    caps_fused<<<grid, 256, 0, stream>>>(x, Wc, Wp, Wa, ba, out);
}

// Round 9
// 121.485 us; speedup vs baseline: 1.1748x; 1.1748x over previous
//
#include <hip/hip_runtime.h>
#include <cmath>

// Caps2dMatwo fused forward: conv3x3 -> pos/app 4x4 transforms -> 3-round routing.
// N=2, T0=4, T1=8, H=W=128, Z=32 (16 pos + 16 app), PD=AD=4.
// R7/R8/R9: R3 structure (32 lanes/pixel, lane = t*4+c; shared xv feeds pos+app).
//  - TH=4 tile (grid 1024, 34.5KB LDS -> 4 blocks/CU, whole grid co-resident)
//  - lean staging: fixed (row,col) per thread, 32-iter z-loop, ~4 VALU/iter
//  - routing iter 0 specialized (r = 0.5 exactly, factor cancels in psquash)

#define TH 4
#define TW 8
#define XR (TH + 2)   // 6 rows incl. halo
#define XC (TW + 2)   // 10 cols incl. halo

__device__ __forceinline__ float qsum4(float v) {
    // sum over the 4 lanes of each quad (lane bits 0-1 = c index)
    int a = __builtin_amdgcn_mov_dpp(__float_as_int(v), 0xB1, 0xF, 0xF, true); // [1,0,3,2]
    v += __int_as_float(a);
    int b = __builtin_amdgcn_mov_dpp(__float_as_int(v), 0x4E, 0xF, 0xF, true); // [2,3,0,1]
    v += __int_as_float(b);
    return v;
}

__global__ __launch_bounds__(256, 4)
void caps_fused(const float* __restrict__ x,    // (2,4,32,128,128)
                const float* __restrict__ Wc,   // (4,3,3,1,8)
                const float* __restrict__ Wp,   // (4,16,8) -> flat [c][128]
                const float* __restrict__ Wa,   // (4,16,8) -> flat [c][128]
                const float* __restrict__ ba,   // (4,8)
                float* __restrict__ out)        // (2,8,32,128,128)
{
    __shared__ float xs[XR][XC][4][36];   // 6*10*4*36*4 = 34560 B

    const int tid = threadIdx.x;
    const int n  = blockIdx.z;
    const int h0 = blockIdx.y * TH;
    const int w0 = blockIdx.x * TW;

    // ---------- stage x halo tile (z-quad XOR swizzle vs banks) ----------
    // thread owns fixed (row,col) = rc = tid&63 (<60) and z-phase tq = tid>>6.
    // iter k stages cz = tq + 4k:  cq = k>>3, z>>2 = k&7, z&3 = tq.
    {
        const int rc = tid & 63;
        const int tq = tid >> 6;
        if (rc < 60) {
            const int row = rc / 10;
            const int col = rc - row * 10;
            const int gh = h0 - 1 + row;
            const int gw = w0 - 1 + col;
            const bool valid = ((unsigned)gh < 128u) & ((unsigned)gw < 128u);
            const int s = rc & 7;
            float* lb = &xs[0][0][0][0] + rc * 144 + tq;
            const float* gp = x + (((size_t)(n * 128 + tq)) << 14)
                                + (gh << 7) + gw;
#pragma unroll
            for (int k = 0; k < 32; ++k) {
                float v = valid ? gp[((size_t)(4 * k)) << 14] : 0.0f;
                lb[(k >> 3) * 36 + (((k & 7) ^ s) << 2)] = v;
            }
        }
    }

    const int p    = tid >> 5;          // pixel column within tile (0..7)
    const int lane = tid & 31;
    const int c    = lane & 3;          // t0 index
    const int t    = lane >> 2;         // output t1 index
    const int chp  = t >> 1;            // conv channel feeding pos part
    const int q0   = (t & 1) << 2;      // z-quad base (0 or 4)

    // ---------- per-thread weights (tiny, cache-hot) ----------
    float wp9[9], wa9[9];
#pragma unroll
    for (int i = 0; i < 9; ++i) {
        wp9[i] = Wc[(c * 9 + i) * 8 + chp];
        wa9[i] = Wc[(c * 9 + i) * 8 + 4 + chp];
    }
    float Mp[16], Ma[16];
#pragma unroll
    for (int q = 0; q < 16; ++q) {
        Mp[q] = Wp[c * 128 + t * 16 + q];   // [j*4+k]
        Ma[q] = Wa[c * 128 + t * 16 + q];
    }
    // column-normalize Mp (sum over j for each column k)
#pragma unroll
    for (int k = 0; k < 4; ++k) {
        float s = Mp[k] * Mp[k] + Mp[4 + k] * Mp[4 + k]
                + Mp[8 + k] * Mp[8 + k] + Mp[12 + k] * Mp[12 + k];
        float inv = __builtin_amdgcn_rsqf(fmaxf(s, 1e-12f));
        Mp[k] *= inv; Mp[4 + k] *= inv; Mp[8 + k] *= inv; Mp[12 + k] *= inv;
    }
    const float bap = ba[c * 8 + t];
    const float wx  = (float)(w0 + p) * (1.0f / 128.0f);

    __syncthreads();

#pragma unroll 1
    for (int g = 0; g < TH; ++g) {
        // ---------- conv 3x3: 16 z values feed both pos & app channels ----------
        float up[16], ua[16];
#pragma unroll
        for (int q = 0; q < 16; ++q) { up[q] = 0.0f; ua[q] = 0.0f; }
#pragma unroll
        for (int dy = 0; dy < 3; ++dy) {
#pragma unroll
            for (int dx = 0; dx < 3; ++dx) {
                const int rr = g + dy, cc = p + dx;
                const int s = (rr * XC + cc) & 7;
                const float* bp = &xs[rr][cc][c][0];
                float xv[16];
                *(float4*)&xv[0]  = *(const float4*)(bp + (((q0 | 0) ^ s) << 2));
                *(float4*)&xv[4]  = *(const float4*)(bp + (((q0 | 1) ^ s) << 2));
                *(float4*)&xv[8]  = *(const float4*)(bp + (((q0 | 2) ^ s) << 2));
                *(float4*)&xv[12] = *(const float4*)(bp + (((q0 | 3) ^ s) << 2));
                const float w1 = wp9[dy * 3 + dx];
                const float w2 = wa9[dy * 3 + dx];
#pragma unroll
                for (int q = 0; q < 16; ++q) {
                    up[q] += xv[q] * w1;
                    ua[q] += xv[q] * w2;
                }
            }
        }

        // ---------- 4x4 transforms -> u_hat[32] ----------
        const float hy = (float)(h0 + g) * (1.0f / 128.0f);
        float uh[32];
#pragma unroll
        for (int i = 0; i < 4; ++i) {
#pragma unroll
            for (int k = 0; k < 4; ++k) {
                uh[i * 4 + k] = up[i * 4 + 0] * Mp[k]
                              + up[i * 4 + 1] * Mp[4 + k]
                              + up[i * 4 + 2] * Mp[8 + k]
                              + up[i * 4 + 3] * Mp[12 + k];
            }
            uh[i * 4 + 0] += up[i * 4 + 3] * wx;   // coord col 0 += w/W
            uh[i * 4 + 1] += up[i * 4 + 3] * hy;   // coord col 1 += h/H
        }
#pragma unroll
        for (int i = 0; i < 4; ++i) {
            const float a0 = ua[i * 4 + 0] + bap;
            const float a1 = ua[i * 4 + 1] + bap;
            const float a2 = ua[i * 4 + 2] + bap;
            const float a3 = ua[i * 4 + 3] + bap;
#pragma unroll
            for (int k = 0; k < 4; ++k)
                uh[16 + i * 4 + k] = a0 * Ma[k] + a1 * Ma[4 + k]
                                   + a2 * Ma[8 + k] + a3 * Ma[12 + k];
        }

        // ---------- routing ----------
        float bacc;
        {   // iter 0: b = 0 -> r = 0.5 exactly; 0.5 cancels inside psquash
            float S[32];
#pragma unroll
            for (int zz = 0; zz < 32; ++zz) S[zz] = qsum4(uh[zz]);
            float m01 = fmaxf(fabsf(S[0]), fabsf(S[1]));
            float m23 = fmaxf(fabsf(S[2]), fabsf(S[3]));
            float m45 = fmaxf(fabsf(S[4]), fabsf(S[5]));
            float m67 = fmaxf(fabsf(S[6]), fabsf(S[7]));
            float m89 = fmaxf(fabsf(S[8]), fabsf(S[9]));
            float mab = fmaxf(fabsf(S[10]), fabsf(S[11]));
            float mcd = fmaxf(fabsf(S[12]), fabsf(S[13]));
            float mef = fmaxf(fabsf(S[14]), fabsf(S[15]));
            const float mxS = fmaxf(fmaxf(fmaxf(m01, m23), fmaxf(m45, m67)),
                                    fmaxf(fmaxf(m89, mab), fmaxf(mcd, mef)));
            float dpS = 0.0f, daS = 0.0f, sqS = 0.0f;
#pragma unroll
            for (int zz = 0; zz < 16; ++zz) dpS += uh[zz] * S[zz];
#pragma unroll
            for (int zz = 16; zz < 32; ++zz) {
                sqS += S[zz] * S[zz];
                daS += uh[zz] * S[zz];
            }
            const float sq = 0.25f * sqS;          // p = 0.5*S
            const float fac = sq * __builtin_amdgcn_rcpf(1.0f + sq)
                                 * __builtin_amdgcn_rsqf(sq + 1e-9f);
            bacc = (dpS * __builtin_amdgcn_rcpf(mxS)) * (0.5f * daS * fac);
        }
#pragma unroll
        for (int it = 1; it < 3; ++it) {
            const float r = __builtin_amdgcn_rcpf(1.0f + __expf(-bacc));
            float pz[32];
#pragma unroll
            for (int zz = 0; zz < 32; ++zz)
                pz[zz] = qsum4(uh[zz] * r);        // reduce over c via DPP (VALU)

            float m01 = fmaxf(fabsf(pz[0]), fabsf(pz[1]));
            float m23 = fmaxf(fabsf(pz[2]), fabsf(pz[3]));
            float m45 = fmaxf(fabsf(pz[4]), fabsf(pz[5]));
            float m67 = fmaxf(fabsf(pz[6]), fabsf(pz[7]));
            float m89 = fmaxf(fabsf(pz[8]), fabsf(pz[9]));
            float mab = fmaxf(fabsf(pz[10]), fabsf(pz[11]));
            float mcd = fmaxf(fabsf(pz[12]), fabsf(pz[13]));
            float mef = fmaxf(fabsf(pz[14]), fabsf(pz[15]));
            const float mx = fmaxf(fmaxf(fmaxf(m01, m23), fmaxf(m45, m67)),
                                   fmaxf(fmaxf(m89, mab), fmaxf(mcd, mef)));
            const float invm = __builtin_amdgcn_rcpf(mx);
            float sq = 0.0f;
#pragma unroll
            for (int zz = 16; zz < 32; ++zz) sq += pz[zz] * pz[zz];
            const float fac = sq * __builtin_amdgcn_rcpf(1.0f + sq)
                                 * __builtin_amdgcn_rsqf(sq + 1e-9f);

            if (it < 2) {
                float dp = 0.0f, da = 0.0f;
#pragma unroll
                for (int zz = 0; zz < 16; ++zz) dp += uh[zz] * pz[zz];
#pragma unroll
                for (int zz = 16; zz < 32; ++zz) da += uh[zz] * pz[zz];
                bacc += (dp * invm) * (da * fac);
            } else if (c == 0) {
                const int row = h0 + g;
                float* ob = out + (((size_t)((n * 8 + t) * 32)) << 14)
                                + (row << 7) + (w0 + p);
#pragma unroll
                for (int zz = 0; zz < 16; ++zz)
                    ob[((size_t)zz) << 14] = pz[zz] * invm;
#pragma unroll
                for (int zz = 16; zz < 32; ++zz)
                    ob[((size_t)zz) << 14] = pz[zz] * fac;
            }
        }
    }
}

extern "C" void kernel_launch(void* const* d_in, const int* in_sizes, int n_in,
                              void* d_out, int out_size, void* d_ws, size_t ws_size,
                              hipStream_t stream) {
    const float* x  = (const float*)d_in[0];
    const float* Wc = (const float*)d_in[1];
    const float* Wp = (const float*)d_in[2];
    const float* Wa = (const float*)d_in[3];
    const float* ba = (const float*)d_in[4];
    float* out = (float*)d_out;

    dim3 grid(128 / TW, 128 / TH, 2);   // (16, 32, 2) = 1024 blocks
    caps_fused<<<grid, 256, 0, stream>>>(x, Wc, Wp, Wa, ba, out);
}